// Round 1
// baseline (925.982 us; speedup 1.0000x reference)
//
#include <hip/hip_runtime.h>

#define NB 8192
#define NT 1024
#define NH 10
// 10 lanes per batch row; 6 rows per wave (lanes 60-63 idle); 4 waves/block -> 24 rows/block
#define ROWS_PER_BLOCK 24

__device__ __forceinline__ float sigm(float x) {
    // 1/(1+e^-x); e^-x -> inf for very negative x gives 0: robust
    return 1.0f / (1.0f + __expf(-x));
}
__device__ __forceinline__ float tanhx(float x) {
    // 1 - 2/(e^{2x}+1); robust at both ends (inf -> 1, 0 -> -1)
    return 1.0f - 2.0f / (__expf(2.0f * x) + 1.0f);
}

__global__ __launch_bounds__(256, 1) void gru_fused(
    const float* __restrict__ X,
    const float* __restrict__ Wih0, const float* __restrict__ Whh0,
    const float* __restrict__ bih0, const float* __restrict__ bhh0,
    const float* __restrict__ Wih1, const float* __restrict__ Whh1,
    const float* __restrict__ bih1, const float* __restrict__ bhh1,
    const float* __restrict__ Wfc,  const float* __restrict__ bfc,
    float* __restrict__ out)
{
    const int tid  = threadIdx.x;
    const int lane = tid & 63;
    const int wave = tid >> 6;
    const int g    = lane / 10;      // group within wave: 0..5 real, 6 = idle lanes
    const int j    = lane - g * 10;  // 0..9: this lane's hidden index / gate row
    const int base = g * 10;         // shfl base lane of this group

    const bool active = (g < 6);
    int b = blockIdx.x * ROWS_PER_BLOCK + wave * 6 + (active ? g : 0);
    const bool store_ok = active && (b < NB);
    if (b >= NB) b = NB - 1;  // clamp so idle/tail lanes load safely

    const int r0 = j, r1 = j + 10, r2 = j + 20;

    // ---- per-lane weight registers (rows r0,r1,r2 of each matrix) ----
    const float w0rx0 = Wih0[r0 * 2 + 0], w0rx1 = Wih0[r0 * 2 + 1];
    const float w0zx0 = Wih0[r1 * 2 + 0], w0zx1 = Wih0[r1 * 2 + 1];
    const float w0nx0 = Wih0[r2 * 2 + 0], w0nx1 = Wih0[r2 * 2 + 1];
    const float br0  = bih0[r0] + bhh0[r0];
    const float bz0  = bih0[r1] + bhh0[r1];
    const float bxn0 = bih0[r2];
    const float bhn0 = bhh0[r2];

    float whr0[NH], whz0[NH], whn0[NH];
    float wir1[NH], wiz1[NH], win1[NH];
    float whr1[NH], whz1[NH], whn1[NH];
#pragma unroll
    for (int k = 0; k < NH; ++k) {
        whr0[k] = Whh0[r0 * NH + k]; whz0[k] = Whh0[r1 * NH + k]; whn0[k] = Whh0[r2 * NH + k];
        wir1[k] = Wih1[r0 * NH + k]; wiz1[k] = Wih1[r1 * NH + k]; win1[k] = Wih1[r2 * NH + k];
        whr1[k] = Whh1[r0 * NH + k]; whz1[k] = Whh1[r1 * NH + k]; whn1[k] = Whh1[r2 * NH + k];
    }
    const float br1  = bih1[r0] + bhh1[r0];
    const float bz1  = bih1[r1] + bhh1[r1];
    const float bxn1 = bih1[r2];
    const float bhn1 = bhh1[r2];

    // ---- state: replicated h0/h1 (constant-indexed), plus this lane's own element ----
    float h0[NH], h1[NH];
#pragma unroll
    for (int k = 0; k < NH; ++k) { h0[k] = 0.0f; h1[k] = 0.0f; }
    float my_h0 = 0.0f, my_h1 = 0.0f;

    const float2* xp = reinterpret_cast<const float2*>(X) + (size_t)b * NT;
    float2 xc = xp[0];

    for (int t = 0; t < NT; ++t) {
        // prefetch next timestep's input (clamped on last iter)
        const float2 xnext = xp[(t + 1 < NT) ? (t + 1) : (NT - 1)];

        // ---------- layer 0 ----------
        float pr = br0  + w0rx0 * xc.x + w0rx1 * xc.y;
        float pz = bz0  + w0zx0 * xc.x + w0zx1 * xc.y;
        float xn = bxn0 + w0nx0 * xc.x + w0nx1 * xc.y;
        float hn = bhn0;
#pragma unroll
        for (int k = 0; k < NH; ++k) {
            pr += whr0[k] * h0[k];
            pz += whz0[k] * h0[k];
            hn += whn0[k] * h0[k];
        }
        const float r = sigm(pr);
        const float z = sigm(pz);
        const float n = tanhx(xn + r * hn);
        my_h0 = n + z * (my_h0 - n);
#pragma unroll
        for (int k = 0; k < NH; ++k) h0[k] = __shfl(my_h0, base + k, 64);

        // ---------- layer 1 (input = h0 at this t) ----------
        float pr1 = br1, pz1 = bz1, xn1 = bxn1, hn1 = bhn1;
#pragma unroll
        for (int k = 0; k < NH; ++k) {
            pr1 += wir1[k] * h0[k];
            pz1 += wiz1[k] * h0[k];
            xn1 += win1[k] * h0[k];
        }
#pragma unroll
        for (int k = 0; k < NH; ++k) {
            pr1 += whr1[k] * h1[k];
            pz1 += whz1[k] * h1[k];
            hn1 += whn1[k] * h1[k];
        }
        const float r1 = sigm(pr1);
        const float z1 = sigm(pz1);
        const float n1 = tanhx(xn1 + r1 * hn1);
        my_h1 = n1 + z1 * (my_h1 - n1);
#pragma unroll
        for (int k = 0; k < NH; ++k) h1[k] = __shfl(my_h1, base + k, 64);

        xc = xnext;
    }

    // ---------- FC head: out[b, o] for o = 0,1 on lanes j=0,1 ----------
    if (store_ok && j < 2) {
        float acc = bfc[j];
#pragma unroll
        for (int k = 0; k < NH; ++k) acc += Wfc[j * NH + k] * h1[k];
        out[(size_t)b * 2 + j] = acc;
    }
}

extern "C" void kernel_launch(void* const* d_in, const int* in_sizes, int n_in,
                              void* d_out, int out_size, void* d_ws, size_t ws_size,
                              hipStream_t stream) {
    const float* X    = (const float*)d_in[0];
    const float* Wih0 = (const float*)d_in[1];
    const float* Whh0 = (const float*)d_in[2];
    const float* bih0 = (const float*)d_in[3];
    const float* bhh0 = (const float*)d_in[4];
    const float* Wih1 = (const float*)d_in[5];
    const float* Whh1 = (const float*)d_in[6];
    const float* bih1 = (const float*)d_in[7];
    const float* bhh1 = (const float*)d_in[8];
    const float* Wfc  = (const float*)d_in[9];
    const float* bfc  = (const float*)d_in[10];
    float* out = (float*)d_out;

    const int grid = (NB + ROWS_PER_BLOCK - 1) / ROWS_PER_BLOCK;  // 342
    gru_fused<<<grid, 256, 0, stream>>>(X, Wih0, Whh0, bih0, bhh0,
                                        Wih1, Whh1, bih1, bhh1, Wfc, bfc, out);
}

// Round 2
// 543.661 us; speedup vs baseline: 1.7032x; 1.7032x over previous
//
#include <hip/hip_runtime.h>

#define NB 8192
#define NT 1024
#define NH 10
#define ROWS_PER_WAVE 4     // 10 lanes/row, lanes 40..63 idle
#define ROWS_PER_BLOCK 16   // 4 waves/block
typedef float v2f __attribute__((ext_vector_type(2)));

__device__ __forceinline__ float rcpf(float x) { return __builtin_amdgcn_rcpf(x); }
__device__ __forceinline__ float sigm(float x) { return rcpf(1.0f + __expf(-x)); }
__device__ __forceinline__ float tanhx(float x) { return 1.0f - 2.0f * rcpf(__expf(2.0f * x) + 1.0f); }
__device__ __forceinline__ float bperm(int addr, float v) {
    return __int_as_float(__builtin_amdgcn_ds_bpermute(addr, __float_as_int(v)));
}
__device__ __forceinline__ float hsum(v2f a) { return a.x + a.y; }

__global__ __launch_bounds__(256, 2) void gru_fused(
    const float* __restrict__ X,
    const float* __restrict__ Wih0, const float* __restrict__ Whh0,
    const float* __restrict__ bih0, const float* __restrict__ bhh0,
    const float* __restrict__ Wih1, const float* __restrict__ Whh1,
    const float* __restrict__ bih1, const float* __restrict__ bhh1,
    const float* __restrict__ Wfc,  const float* __restrict__ bfc,
    float* __restrict__ out)
{
    const int tid  = threadIdx.x;
    const int lane = tid & 63;
    const int wave = tid >> 6;
    const int g    = lane / 10;      // group in wave: 0..3 real, 4..6 idle
    const int j    = lane - g * 10;  // 0..9: this lane's hidden/gate index
    const int base = g * 10;

    const bool active = (g < ROWS_PER_WAVE);
    int b = blockIdx.x * ROWS_PER_BLOCK + wave * ROWS_PER_WAVE + (active ? g : 0);
    const bool store_ok = active && (b < NB);
    if (b >= NB) b = NB - 1;

    const int r0 = j, r1 = j + 10, r2 = j + 20;

    // ---- per-lane weights, packed as float2 (rows are 40B -> 8B aligned) ----
    const v2f wxr = *reinterpret_cast<const v2f*>(Wih0 + r0 * 2);
    const v2f wxz = *reinterpret_cast<const v2f*>(Wih0 + r1 * 2);
    const v2f wxn = *reinterpret_cast<const v2f*>(Wih0 + r2 * 2);

    v2f whr0[5], whz0[5], whn0[5];
    v2f wir1[5], wiz1[5], win1[5];
    v2f whr1[5], whz1[5], whn1[5];
#pragma unroll
    for (int k = 0; k < 5; ++k) {
        whr0[k] = *reinterpret_cast<const v2f*>(Whh0 + r0 * NH + 2 * k);
        whz0[k] = *reinterpret_cast<const v2f*>(Whh0 + r1 * NH + 2 * k);
        whn0[k] = *reinterpret_cast<const v2f*>(Whh0 + r2 * NH + 2 * k);
        wir1[k] = *reinterpret_cast<const v2f*>(Wih1 + r0 * NH + 2 * k);
        wiz1[k] = *reinterpret_cast<const v2f*>(Wih1 + r1 * NH + 2 * k);
        win1[k] = *reinterpret_cast<const v2f*>(Wih1 + r2 * NH + 2 * k);
        whr1[k] = *reinterpret_cast<const v2f*>(Whh1 + r0 * NH + 2 * k);
        whz1[k] = *reinterpret_cast<const v2f*>(Whh1 + r1 * NH + 2 * k);
        whn1[k] = *reinterpret_cast<const v2f*>(Whh1 + r2 * NH + 2 * k);
    }
    const float br0  = bih0[r0] + bhh0[r0];
    const float bz0  = bih0[r1] + bhh0[r1];
    const float bxn0 = bih0[r2];
    const float bhn0 = bhh0[r2];
    const float br1  = bih1[r0] + bhh1[r0];
    const float bz1  = bih1[r1] + bhh1[r1];
    const float bxn1 = bih1[r2];
    const float bhn1 = bhh1[r2];

    // precomputed bpermute byte addresses for the 10-lane broadcast
    int ad[NH];
#pragma unroll
    for (int k = 0; k < NH; ++k) ad[k] = (base + k) << 2;

    v2f h0p[5], h1p[5];
#pragma unroll
    for (int k = 0; k < 5; ++k) { h0p[k] = (v2f){0.f, 0.f}; h1p[k] = (v2f){0.f, 0.f}; }
    float my_h0 = 0.0f, my_h1 = 0.0f;

    const float2* xp = reinterpret_cast<const float2*>(X) + (size_t)b * NT;
    float2 xc = xp[0];

    for (int t = 0; t < NT; ++t) {
        const float2 xnext = xp[(t + 1 < NT) ? (t + 1) : (NT - 1)];
        const v2f xv = {xc.x, xc.y};

        // ---------- layer 0 ----------
        v2f ar = wxr * xv;
        v2f az = wxz * xv;
        v2f anx = wxn * xv;
        v2f anh = {0.f, 0.f};
#pragma unroll
        for (int k = 0; k < 5; ++k) {
            ar  += whr0[k] * h0p[k];
            az  += whz0[k] * h0p[k];
            anh += whn0[k] * h0p[k];
        }
        const float r = sigm(br0 + hsum(ar));
        const float z = sigm(bz0 + hsum(az));
        const float n = tanhx(bxn0 + hsum(anx) + r * (bhn0 + hsum(anh)));
        my_h0 = n + z * (my_h0 - n);
#pragma unroll
        for (int k = 0; k < 5; ++k) {
            h0p[k].x = bperm(ad[2 * k],     my_h0);
            h0p[k].y = bperm(ad[2 * k + 1], my_h0);
        }

        // ---------- layer 1 ----------
        v2f a1r = {0.f, 0.f}, a1z = {0.f, 0.f}, a1n = {0.f, 0.f}, a1h = {0.f, 0.f};
#pragma unroll
        for (int k = 0; k < 5; ++k) {
            a1r += wir1[k] * h0p[k];
            a1z += wiz1[k] * h0p[k];
            a1n += win1[k] * h0p[k];
        }
#pragma unroll
        for (int k = 0; k < 5; ++k) {
            a1r += whr1[k] * h1p[k];
            a1z += whz1[k] * h1p[k];
            a1h += whn1[k] * h1p[k];
        }
        const float r1 = sigm(br1 + hsum(a1r));
        const float z1 = sigm(bz1 + hsum(a1z));
        const float n1 = tanhx(bxn1 + hsum(a1n) + r1 * (bhn1 + hsum(a1h)));
        my_h1 = n1 + z1 * (my_h1 - n1);
#pragma unroll
        for (int k = 0; k < 5; ++k) {
            h1p[k].x = bperm(ad[2 * k],     my_h1);
            h1p[k].y = bperm(ad[2 * k + 1], my_h1);
        }

        xc = xnext;
    }

    // ---------- FC head ----------
    if (store_ok && j < 2) {
        float acc = bfc[j];
#pragma unroll
        for (int k = 0; k < 5; ++k)
            acc += Wfc[j * NH + 2 * k] * h1p[k].x + Wfc[j * NH + 2 * k + 1] * h1p[k].y;
        out[(size_t)b * 2 + j] = acc;
    }
}

extern "C" void kernel_launch(void* const* d_in, const int* in_sizes, int n_in,
                              void* d_out, int out_size, void* d_ws, size_t ws_size,
                              hipStream_t stream) {
    const float* X    = (const float*)d_in[0];
    const float* Wih0 = (const float*)d_in[1];
    const float* Whh0 = (const float*)d_in[2];
    const float* bih0 = (const float*)d_in[3];
    const float* bhh0 = (const float*)d_in[4];
    const float* Wih1 = (const float*)d_in[5];
    const float* Whh1 = (const float*)d_in[6];
    const float* bih1 = (const float*)d_in[7];
    const float* bhh1 = (const float*)d_in[8];
    const float* Wfc  = (const float*)d_in[9];
    const float* bfc  = (const float*)d_in[10];
    float* out = (float*)d_out;

    const int grid = NB / ROWS_PER_BLOCK;  // 512 blocks -> 2048 waves = 2/SIMD exactly
    gru_fused<<<grid, 256, 0, stream>>>(X, Wih0, Whh0, bih0, bhh0,
                                        Wih1, Whh1, bih1, bhh1, Wfc, bfc, out);
}

// Round 3
// 542.975 us; speedup vs baseline: 1.7054x; 1.0013x over previous
//
#include <hip/hip_runtime.h>

#define NB 8192
#define NT 1024
#define NH 10
#define ROWS_PER_WAVE 4     // 10 lanes/row, lanes 40..63 idle
#define ROWS_PER_BLOCK 16   // 4 waves/block
typedef float v2f __attribute__((ext_vector_type(2)));

__device__ __forceinline__ float rcpf(float x) { return __builtin_amdgcn_rcpf(x); }
__device__ __forceinline__ float sigm(float x) { return rcpf(1.0f + __expf(-x)); }
__device__ __forceinline__ float tanhx(float x) { return 1.0f - 2.0f * rcpf(__expf(2.0f * x) + 1.0f); }
__device__ __forceinline__ float bperm(int addr, float v) {
    return __int_as_float(__builtin_amdgcn_ds_bpermute(addr, __float_as_int(v)));
}
__device__ __forceinline__ float hsum(v2f a) { return a.x + a.y; }
// Pin a value into VGPRs: opaque to LICM/remat, so the weights stay resident
// instead of being re-loaded from L1 every timestep (R1: VGPR=80 < 90 needed).
__device__ __forceinline__ void pin(v2f& w)  { asm volatile("" : "+v"(w)); }
__device__ __forceinline__ void pinf(float& w){ asm volatile("" : "+v"(w)); }

__global__ __launch_bounds__(256, 2) void gru_fused(
    const float* __restrict__ X,
    const float* __restrict__ Wih0, const float* __restrict__ Whh0,
    const float* __restrict__ bih0, const float* __restrict__ bhh0,
    const float* __restrict__ Wih1, const float* __restrict__ Whh1,
    const float* __restrict__ bih1, const float* __restrict__ bhh1,
    const float* __restrict__ Wfc,  const float* __restrict__ bfc,
    float* __restrict__ out)
{
    const int tid  = threadIdx.x;
    const int lane = tid & 63;
    const int wave = tid >> 6;
    const int g    = lane / 10;      // group in wave: 0..3 real, 4..6 idle
    const int j    = lane - g * 10;  // 0..9: this lane's hidden/gate index
    const int base = g * 10;

    const bool active = (g < ROWS_PER_WAVE);
    int b = blockIdx.x * ROWS_PER_BLOCK + wave * ROWS_PER_WAVE + (active ? g : 0);
    const bool store_ok = active && (b < NB);
    if (b >= NB) b = NB - 1;

    const int r0 = j, r1 = j + 10, r2 = j + 20;

    // ---- per-lane weights, packed as float2 (rows are 40B -> 8B aligned) ----
    v2f wxr = *reinterpret_cast<const v2f*>(Wih0 + r0 * 2);
    v2f wxz = *reinterpret_cast<const v2f*>(Wih0 + r1 * 2);
    v2f wxn = *reinterpret_cast<const v2f*>(Wih0 + r2 * 2);
    pin(wxr); pin(wxz); pin(wxn);

    v2f whr0[5], whz0[5], whn0[5];
    v2f wir1[5], wiz1[5], win1[5];
    v2f whr1[5], whz1[5], whn1[5];
#pragma unroll
    for (int k = 0; k < 5; ++k) {
        whr0[k] = *reinterpret_cast<const v2f*>(Whh0 + r0 * NH + 2 * k);
        whz0[k] = *reinterpret_cast<const v2f*>(Whh0 + r1 * NH + 2 * k);
        whn0[k] = *reinterpret_cast<const v2f*>(Whh0 + r2 * NH + 2 * k);
        wir1[k] = *reinterpret_cast<const v2f*>(Wih1 + r0 * NH + 2 * k);
        wiz1[k] = *reinterpret_cast<const v2f*>(Wih1 + r1 * NH + 2 * k);
        win1[k] = *reinterpret_cast<const v2f*>(Wih1 + r2 * NH + 2 * k);
        whr1[k] = *reinterpret_cast<const v2f*>(Whh1 + r0 * NH + 2 * k);
        whz1[k] = *reinterpret_cast<const v2f*>(Whh1 + r1 * NH + 2 * k);
        whn1[k] = *reinterpret_cast<const v2f*>(Whh1 + r2 * NH + 2 * k);
        pin(whr0[k]); pin(whz0[k]); pin(whn0[k]);
        pin(wir1[k]); pin(wiz1[k]); pin(win1[k]);
        pin(whr1[k]); pin(whz1[k]); pin(whn1[k]);
    }
    float br0  = bih0[r0] + bhh0[r0];
    float bz0  = bih0[r1] + bhh0[r1];
    float bxn0 = bih0[r2];
    float bhn0 = bhh0[r2];
    float br1  = bih1[r0] + bhh1[r0];
    float bz1  = bih1[r1] + bhh1[r1];
    float bxn1 = bih1[r2];
    float bhn1 = bhh1[r2];
    pinf(br0); pinf(bz0); pinf(bxn0); pinf(bhn0);
    pinf(br1); pinf(bz1); pinf(bxn1); pinf(bhn1);

    // bpermute base byte address; +4k folds into the DS offset immediate
    const int ad0 = base << 2;

    v2f h0p[5], h1p[5];
#pragma unroll
    for (int k = 0; k < 5; ++k) { h0p[k] = (v2f){0.f, 0.f}; h1p[k] = (v2f){0.f, 0.f}; }
    float my_h0 = 0.0f, my_h1 = 0.0f;

    const float2* xp = reinterpret_cast<const float2*>(X) + (size_t)b * NT;
    float2 xc = xp[0];

    for (int t = 0; t < NT; ++t) {
        const float2 xnext = xp[(t + 1 < NT) ? (t + 1) : (NT - 1)];
        const v2f xv = {xc.x, xc.y};

        // ---------- layer 0 ----------
        v2f ar = wxr * xv;
        v2f az = wxz * xv;
        v2f anx = wxn * xv;
        v2f anh = {0.f, 0.f};
#pragma unroll
        for (int k = 0; k < 5; ++k) {
            ar  += whr0[k] * h0p[k];
            az  += whz0[k] * h0p[k];
            anh += whn0[k] * h0p[k];
        }
        const float r = sigm(br0 + hsum(ar));
        const float z = sigm(bz0 + hsum(az));
        const float n = tanhx(bxn0 + hsum(anx) + r * (bhn0 + hsum(anh)));
        my_h0 = n + z * (my_h0 - n);
#pragma unroll
        for (int k = 0; k < 5; ++k) {
            h0p[k].x = bperm(ad0 + 8 * k,     my_h0);
            h0p[k].y = bperm(ad0 + 8 * k + 4, my_h0);
        }

        // ---------- layer 1 ----------
        v2f a1r = {0.f, 0.f}, a1z = {0.f, 0.f}, a1n = {0.f, 0.f}, a1h = {0.f, 0.f};
#pragma unroll
        for (int k = 0; k < 5; ++k) {
            a1r += wir1[k] * h0p[k];
            a1z += wiz1[k] * h0p[k];
            a1n += win1[k] * h0p[k];
        }
#pragma unroll
        for (int k = 0; k < 5; ++k) {
            a1r += whr1[k] * h1p[k];
            a1z += whz1[k] * h1p[k];
            a1h += whn1[k] * h1p[k];
        }
        const float r1 = sigm(br1 + hsum(a1r));
        const float z1 = sigm(bz1 + hsum(a1z));
        const float n1 = tanhx(bxn1 + hsum(a1n) + r1 * (bhn1 + hsum(a1h)));
        my_h1 = n1 + z1 * (my_h1 - n1);
#pragma unroll
        for (int k = 0; k < 5; ++k) {
            h1p[k].x = bperm(ad0 + 8 * k,     my_h1);
            h1p[k].y = bperm(ad0 + 8 * k + 4, my_h1);
        }

        xc = xnext;
    }

    // ---------- FC head ----------
    if (store_ok && j < 2) {
        float acc = bfc[j];
#pragma unroll
        for (int k = 0; k < 5; ++k)
            acc += Wfc[j * NH + 2 * k] * h1p[k].x + Wfc[j * NH + 2 * k + 1] * h1p[k].y;
        out[(size_t)b * 2 + j] = acc;
    }
}

extern "C" void kernel_launch(void* const* d_in, const int* in_sizes, int n_in,
                              void* d_out, int out_size, void* d_ws, size_t ws_size,
                              hipStream_t stream) {
    const float* X    = (const float*)d_in[0];
    const float* Wih0 = (const float*)d_in[1];
    const float* Whh0 = (const float*)d_in[2];
    const float* bih0 = (const float*)d_in[3];
    const float* bhh0 = (const float*)d_in[4];
    const float* Wih1 = (const float*)d_in[5];
    const float* Whh1 = (const float*)d_in[6];
    const float* bih1 = (const float*)d_in[7];
    const float* bhh1 = (const float*)d_in[8];
    const float* Wfc  = (const float*)d_in[9];
    const float* bfc  = (const float*)d_in[10];
    float* out = (float*)d_out;

    const int grid = NB / ROWS_PER_BLOCK;  // 512 blocks -> 2048 waves = 2/SIMD exactly
    gru_fused<<<grid, 256, 0, stream>>>(X, Wih0, Whh0, bih0, bhh0,
                                        Wih1, Whh1, bih1, bhh1, Wfc, bfc, out);
}